// Round 2
// baseline (1113.700 us; speedup 1.0000x reference)
//
#include <hip/hip_runtime.h>
#include <hip/hip_bf16.h>
#include <float.h>

// Problem constants
#define B_      32
#define HID_    4096
#define NH_     32
#define NKV_    8
#define G_      4
#define HD_     128
#define QKVC_   6144      // (NH + 2*NKV) * HD
#define S_      2048
#define BS_     16
#define MAXB_   128

// Split-K config
#define KS1     16        // qkv GEMM k-split (4096/16 = 256 rows/chunk)
#define HCH1    256
#define NCHUNK  8         // attention S-chunks
#define CHUNK_  256
#define KS2     16        // o-proj k-split
#define HCH2    256

// ws layout (float offsets)
#define OFF_QKVP 0ull
#define SZ_QKVP  ((size_t)KS1 * 32 * QKVC_)          // 3,145,728
#define OFF_QR   (OFF_QKVP + SZ_QKVP)
#define SZ_QR    ((size_t)32 * 4096)
#define OFF_ATTP (OFF_QR + SZ_QR)
#define SZ_ATTP  ((size_t)32 * 8 * NCHUNK * 4 * 132)
#define OFF_ATTO (OFF_ATTP + SZ_ATTP)
#define SZ_ATTO  ((size_t)32 * 4096)
#define OFF_OP   (OFF_ATTO + SZ_ATTO)
#define SZ_OP    ((size_t)KS2 * 32 * 4096)

// ---------------- Kernel 1: QKV GEMM split-K partials ----------------
// grid (24, KS1), block 256. thread = one output column, 32 batch accumulators.
// hidden[] reads are wave-uniform -> scalar loads; w column reads coalesced.
__global__ __launch_bounds__(256) void k_qkv_partial(
    const float* __restrict__ hidden, const float* __restrict__ w,
    float* __restrict__ part) {
  const int col = blockIdx.x * 256 + threadIdx.x;
  const int kc  = blockIdx.y;
  const int h0  = kc * HCH1;
  float acc[32];
#pragma unroll
  for (int b = 0; b < 32; ++b) acc[b] = 0.f;
  const float* wp = w + (size_t)h0 * QKVC_ + col;
  for (int h = 0; h < HCH1; ++h) {
    float wv = wp[(size_t)h * QKVC_];
#pragma unroll
    for (int b = 0; b < 32; ++b)
      acc[b] = fmaf(hidden[b * HID_ + h0 + h], wv, acc[b]);
  }
  float* pp = part + (size_t)kc * 32 * QKVC_ + col;
#pragma unroll
  for (int b = 0; b < 32; ++b) pp[(size_t)b * QKVC_] = acc[b];
}

// ---------------- Kernel 2: reduce partials + RoPE + cache scatter ----------------
// grid (32 b, 6 head-groups of 8 combined heads), block 256.
// combined head H: 0..31 q, 32..39 k, 40..47 v
__global__ __launch_bounds__(256) void k_rope_scatter(
    const float* __restrict__ part, const int* __restrict__ positions,
    const int* __restrict__ loc, float* __restrict__ qr,
    float* __restrict__ kcache, float* __restrict__ vcache) {
  const int b  = blockIdx.x;
  const int hg = blockIdx.y;
  __shared__ float row[1024];
  const int colbase = hg * 1024;
  for (int t = threadIdx.x; t < 1024; t += 256) {
    int col = colbase + t;
    float s = 0.f;
#pragma unroll
    for (int kc = 0; kc < KS1; ++kc)
      s += part[((size_t)kc * 32 + b) * QKVC_ + col];
    row[t] = s;
  }
  __syncthreads();
  const int pos = positions[b];
  const int lc  = loc[b];
  const float fpos = (float)pos;
  for (int t = threadIdx.x; t < 1024; t += 256) {
    int col  = colbase + t;
    int head = col >> 7;
    int d    = col & 127;
    float val;
    if (head < 40) {
      int dr = d & 63;
      float inv = 1.0f / powf(500000.0f, (float)dr * (1.0f / 64.0f));
      float f = fpos * inv;
      float c = cosf(f), sn = sinf(f);
      float x1 = row[(t & ~127) | dr];
      float x2 = row[(t & ~127) | (dr + 64)];
      val = (d < 64) ? (x1 * c - x2 * sn) : (x2 * c + x1 * sn);
    } else {
      val = row[t];
    }
    if (head < 32) {
      qr[(size_t)b * 4096 + col] = val;
    } else if (head < 40) {
      kcache[((size_t)lc * NKV_ + (head - 32)) * HD_ + d] = val;
    } else {
      vcache[((size_t)lc * NKV_ + (head - 40)) * HD_ + d] = val;
    }
  }
}

// ---------------- Kernel 3: flash-decode attention partials ----------------
// grid (32 b, 8 kv, 8 chunk), block 256 = 8 half-waves; half-wave = one K/V row
// (32 lanes x float4 = 128 floats, coalesced).
__global__ __launch_bounds__(256) void k_attn_partial(
    const float* __restrict__ qr, const float* __restrict__ kcache,
    const float* __restrict__ vcache, const int* __restrict__ positions,
    const int* __restrict__ btab, float* __restrict__ part) {
  const int b = blockIdx.x, kv = blockIdx.y, ck = blockIdx.z;
  const int tid = threadIdx.x;
  const int hw = tid >> 5, ln = tid & 31;
  const int pos = positions[b];
  const int c0 = ck * CHUNK_;
  float* pout = part + ((size_t)(b * 8 + kv) * NCHUNK + ck) * 4 * 132;

  __shared__ float s_lds[CHUNK_ * 4];
  __shared__ int   slot_lds[CHUNK_];
  __shared__ float red[8 * 512];
  __shared__ float ml[8];

  if (c0 > pos) {  // fully-masked chunk: m=-FLT_MAX, l=0, acc=0
    for (int o = tid; o < 4 * 132; o += 256) pout[o] = 0.f;
    if (tid < 4) pout[tid * 132] = -FLT_MAX;
    return;
  }
  const int nrow = min(CHUNK_, pos + 1 - c0);

  for (int i = tid; i < CHUNK_ * 4; i += 256) s_lds[i] = -FLT_MAX;
  __syncthreads();

  float4 qf[4];
#pragma unroll
  for (int g = 0; g < 4; ++g)
    qf[g] = *reinterpret_cast<const float4*>(
        qr + (size_t)b * 4096 + (size_t)(kv * 4 + g) * 128 + 4 * ln);
  const float scale = 0.08838834764831845f;

  // Phase A: scores
  for (int r = hw; r < nrow; r += 8) {
    int j = c0 + r;
    int slot = btab[b * MAXB_ + (j >> 4)] * BS_ + (j & 15);
    if (ln == 0) slot_lds[r] = slot;
    const float4 kf = *reinterpret_cast<const float4*>(
        kcache + ((size_t)slot * NKV_ + kv) * HD_ + 4 * ln);
#pragma unroll
    for (int g = 0; g < 4; ++g) {
      float s = qf[g].x * kf.x + qf[g].y * kf.y + qf[g].z * kf.z + qf[g].w * kf.w;
      s += __shfl_xor(s, 16); s += __shfl_xor(s, 8); s += __shfl_xor(s, 4);
      s += __shfl_xor(s, 2);  s += __shfl_xor(s, 1);
      if (ln == 0) s_lds[r * 4 + g] = s * scale;
    }
  }
  __syncthreads();

  // softmax partial: wave w owns head-group g=w, 64 lanes cover 256 rows
  {
    int w = tid >> 6, lane = tid & 63;
    float v0 = s_lds[lane * 4 + w];
    float v1 = s_lds[(lane + 64) * 4 + w];
    float v2 = s_lds[(lane + 128) * 4 + w];
    float v3 = s_lds[(lane + 192) * 4 + w];
    float m = fmaxf(fmaxf(v0, v1), fmaxf(v2, v3));
#pragma unroll
    for (int off = 32; off; off >>= 1) m = fmaxf(m, __shfl_xor(m, off));
    float p0 = __expf(v0 - m), p1 = __expf(v1 - m);
    float p2 = __expf(v2 - m), p3 = __expf(v3 - m);
    float l = p0 + p1 + p2 + p3;
#pragma unroll
    for (int off = 32; off; off >>= 1) l += __shfl_xor(l, off);
    s_lds[lane * 4 + w] = p0;
    s_lds[(lane + 64) * 4 + w] = p1;
    s_lds[(lane + 128) * 4 + w] = p2;
    s_lds[(lane + 192) * 4 + w] = p3;
    if (lane == 0) { ml[w] = m; ml[4 + w] = l; }
  }
  __syncthreads();

  // Phase B: P·V
  float acc[4][4];
#pragma unroll
  for (int g = 0; g < 4; ++g)
#pragma unroll
    for (int i = 0; i < 4; ++i) acc[g][i] = 0.f;
  for (int r = hw; r < nrow; r += 8) {
    int slot = slot_lds[r];
    const float4 vf = *reinterpret_cast<const float4*>(
        vcache + ((size_t)slot * NKV_ + kv) * HD_ + 4 * ln);
#pragma unroll
    for (int g = 0; g < 4; ++g) {
      float pg = s_lds[r * 4 + g];
      acc[g][0] = fmaf(pg, vf.x, acc[g][0]);
      acc[g][1] = fmaf(pg, vf.y, acc[g][1]);
      acc[g][2] = fmaf(pg, vf.z, acc[g][2]);
      acc[g][3] = fmaf(pg, vf.w, acc[g][3]);
    }
  }
#pragma unroll
  for (int g = 0; g < 4; ++g) {
    red[hw * 512 + g * 128 + 4 * ln + 0] = acc[g][0];
    red[hw * 512 + g * 128 + 4 * ln + 1] = acc[g][1];
    red[hw * 512 + g * 128 + 4 * ln + 2] = acc[g][2];
    red[hw * 512 + g * 128 + 4 * ln + 3] = acc[g][3];
  }
  __syncthreads();
  for (int o = tid; o < 512; o += 256) {
    float s = 0.f;
#pragma unroll
    for (int h = 0; h < 8; ++h) s += red[h * 512 + o];
    int g = o >> 7, d = o & 127;
    pout[g * 132 + 2 + d] = s;
  }
  if (tid < 4) { pout[tid * 132 + 0] = ml[tid]; pout[tid * 132 + 1] = ml[4 + tid]; }
}

// ---------------- Kernel 4: merge attention chunks ----------------
// grid (32, 8), block 256
__global__ __launch_bounds__(256) void k_attn_reduce(
    const float* __restrict__ part, float* __restrict__ attnO) {
  const int b = blockIdx.x, kv = blockIdx.y;
  const float* pb = part + (size_t)(b * 8 + kv) * NCHUNK * 4 * 132;
  for (int o = threadIdx.x; o < 512; o += 256) {
    int g = o >> 7, d = o & 127;
    float m = -FLT_MAX;
#pragma unroll
    for (int c = 0; c < NCHUNK; ++c) m = fmaxf(m, pb[(c * 4 + g) * 132]);
    float l = 0.f, s = 0.f;
#pragma unroll
    for (int c = 0; c < NCHUNK; ++c) {
      float mc = pb[(c * 4 + g) * 132];
      float wgt = __expf(mc - m);
      l = fmaf(pb[(c * 4 + g) * 132 + 1], wgt, l);
      s = fmaf(pb[(c * 4 + g) * 132 + 2 + d], wgt, s);
    }
    attnO[(size_t)b * 4096 + (size_t)(kv * 4 + g) * 128 + d] = s / l;
  }
}

// ---------------- Kernel 5: output GEMM split-K partials ----------------
// grid (16, KS2), block 256
__global__ __launch_bounds__(256) void k_oproj_partial(
    const float* __restrict__ attnO, const float* __restrict__ wo,
    float* __restrict__ part) {
  const int col = blockIdx.x * 256 + threadIdx.x;
  const int kc  = blockIdx.y;
  const int h0  = kc * HCH2;
  float acc[32];
#pragma unroll
  for (int b = 0; b < 32; ++b) acc[b] = 0.f;
  const float* wp = wo + (size_t)h0 * 4096 + col;
  for (int h = 0; h < HCH2; ++h) {
    float wv = wp[(size_t)h * 4096];
#pragma unroll
    for (int b = 0; b < 32; ++b)
      acc[b] = fmaf(attnO[b * 4096 + h0 + h], wv, acc[b]);
  }
  float* pp = part + (size_t)kc * 32 * 4096 + col;
#pragma unroll
  for (int b = 0; b < 32; ++b) pp[(size_t)b * 4096] = acc[b];
}

// ---------------- Kernel 6: final reduce ----------------
// 32*4096 = 131072 outputs; grid 512 x 256
__global__ __launch_bounds__(256) void k_final_reduce(
    const float* __restrict__ part, float* __restrict__ out) {
  size_t idx = (size_t)blockIdx.x * 256 + threadIdx.x;
  float s = 0.f;
#pragma unroll
  for (int kc = 0; kc < KS2; ++kc) s += part[(size_t)kc * 131072 + idx];
  out[idx] = s;
}

extern "C" void kernel_launch(void* const* d_in, const int* in_sizes, int n_in,
                              void* d_out, int out_size, void* d_ws, size_t ws_size,
                              hipStream_t stream) {
  const float* hidden = (const float*)d_in[0];
  const float* w_qkv  = (const float*)d_in[1];
  const float* w_o    = (const float*)d_in[2];
  float* k_cache      = (float*)d_in[3];
  float* v_cache      = (float*)d_in[4];
  const int* positions = (const int*)d_in[5];
  const int* btab      = (const int*)d_in[6];
  const int* loc       = (const int*)d_in[7];

  float* ws   = (float*)d_ws;
  float* qkvP = ws + OFF_QKVP;
  float* qR   = ws + OFF_QR;
  float* attP = ws + OFF_ATTP;
  float* attO = ws + OFF_ATTO;
  float* oP   = ws + OFF_OP;
  float* out  = (float*)d_out;

  k_qkv_partial<<<dim3(QKVC_ / 256, KS1), 256, 0, stream>>>(hidden, w_qkv, qkvP);
  k_rope_scatter<<<dim3(B_, 6), 256, 0, stream>>>(qkvP, positions, loc, qR, k_cache, v_cache);
  k_attn_partial<<<dim3(B_, NKV_, NCHUNK), 256, 0, stream>>>(qR, k_cache, v_cache,
                                                             positions, btab, attP);
  k_attn_reduce<<<dim3(B_, NKV_), 256, 0, stream>>>(attP, attO);
  k_oproj_partial<<<dim3(4096 / 256, KS2), 256, 0, stream>>>(attO, w_o, oP);
  k_final_reduce<<<512, 256, 0, stream>>>(oP, out);
}

// Round 4
// 746.240 us; speedup vs baseline: 1.4924x; 1.4924x over previous
//
#include <hip/hip_runtime.h>
#include <hip/hip_bf16.h>
#include <float.h>

// Problem constants
#define B_      32
#define HID_    4096
#define NH_     32
#define NKV_    8
#define G_      4
#define HD_     128
#define QKVC_   6144      // (NH + 2*NKV) * HD
#define S_      2048
#define BS_     16
#define MAXB_   128

// Split-K config
#define KS1     32        // qkv GEMM k-split (4096/32 = 128 rows/chunk)
#define HCH1    128
#define NCHUNK  8         // attention S-chunks
#define CHUNK_  256
#define KS2     32        // o-proj k-split
#define HCH2    128

// ws layout (float offsets)
#define OFF_QKVP 0ull
#define SZ_QKVP  ((size_t)KS1 * 32 * QKVC_)          // 6,291,456
#define OFF_QR   (OFF_QKVP + SZ_QKVP)
#define SZ_QR    ((size_t)32 * 4096)
#define OFF_ATTP (OFF_QR + SZ_QR)
#define SZ_ATTP  ((size_t)32 * 8 * NCHUNK * 4 * 132)
#define OFF_ATTO (OFF_ATTP + SZ_ATTP)
#define SZ_ATTO  ((size_t)32 * 4096)
#define OFF_OP   (OFF_ATTO + SZ_ATTO)
#define SZ_OP    ((size_t)KS2 * 32 * 4096)           // 4,194,304

#define REP32(X) X(0)X(1)X(2)X(3)X(4)X(5)X(6)X(7)X(8)X(9)X(10)X(11)X(12)X(13)X(14)X(15)X(16)X(17)X(18)X(19)X(20)X(21)X(22)X(23)X(24)X(25)X(26)X(27)X(28)X(29)X(30)X(31)

// ---------------- Kernel 1: QKV GEMM split-K partials ----------------
// grid (24, KS1), block 256. thread = one output column, 32 NAMED batch
// accumulators (cannot be demoted to scratch). hidden reads are wave-uniform
// -> scalar s_load; w column reads coalesced (256B/wave-inst), 4 in flight
// via unroll.
__global__ __launch_bounds__(256) void k_qkv_partial(
    const float* __restrict__ hidden, const float* __restrict__ w,
    float* __restrict__ part) {
  const int col = blockIdx.x * 256 + threadIdx.x;
  const int kc  = blockIdx.y;
  const int h0  = kc * HCH1;
#define DECL(i) float a##i = 0.f;
  REP32(DECL)
#undef DECL
  const float* wp = w + (size_t)h0 * QKVC_ + col;
  const float* hp = hidden + h0;
#pragma unroll 4
  for (int h = 0; h < HCH1; ++h) {
    float wv = wp[(size_t)h * QKVC_];
#define FMA(i) a##i = fmaf(hp[i * HID_ + h], wv, a##i);
    REP32(FMA)
#undef FMA
  }
  float* pp = part + (size_t)kc * 32 * QKVC_ + col;
#define ST(i) pp[(size_t)i * QKVC_] = a##i;
  REP32(ST)
#undef ST
}

// ---------------- Kernel 2: reduce partials + RoPE + cache scatter ----------------
// grid (32 b, 6 head-groups of 8 combined heads), block 256.
// combined head H: 0..31 q, 32..39 k, 40..47 v
__global__ __launch_bounds__(256) void k_rope_scatter(
    const float* __restrict__ part, const int* __restrict__ positions,
    const int* __restrict__ loc, float* __restrict__ qr,
    float* __restrict__ kcache, float* __restrict__ vcache) {
  const int b  = blockIdx.x;
  const int hg = blockIdx.y;
  __shared__ float row[1024];
  const int colbase = hg * 1024;
  for (int t = threadIdx.x; t < 1024; t += 256) {
    int col = colbase + t;
    float s = 0.f;
#pragma unroll
    for (int kc = 0; kc < KS1; ++kc)
      s += part[((size_t)kc * 32 + b) * QKVC_ + col];
    row[t] = s;
  }
  __syncthreads();
  const int pos = positions[b];
  const int lc  = loc[b];
  const float fpos = (float)pos;
  for (int t = threadIdx.x; t < 1024; t += 256) {
    int col  = colbase + t;
    int head = col >> 7;
    int d    = col & 127;
    float val;
    if (head < 40) {
      int dr = d & 63;
      float inv = 1.0f / powf(500000.0f, (float)dr * (1.0f / 64.0f));
      float f = fpos * inv;
      float c = cosf(f), sn = sinf(f);
      float x1 = row[(t & ~127) | dr];
      float x2 = row[(t & ~127) | (dr + 64)];
      val = (d < 64) ? (x1 * c - x2 * sn) : (x2 * c + x1 * sn);
    } else {
      val = row[t];
    }
    if (head < 32) {
      qr[(size_t)b * 4096 + col] = val;
    } else if (head < 40) {
      kcache[((size_t)lc * NKV_ + (head - 32)) * HD_ + d] = val;
    } else {
      vcache[((size_t)lc * NKV_ + (head - 40)) * HD_ + d] = val;
    }
  }
}

// ---------------- Kernel 3: flash-decode attention partials ----------------
// grid (32 b, 8 kv, 8 chunk), block 256 = 8 half-waves; half-wave = one K/V row
// (32 lanes x float4 = 128 floats, coalesced). 2048 blocks = full occupancy.
__global__ __launch_bounds__(256) void k_attn_partial(
    const float* __restrict__ qr, const float* __restrict__ kcache,
    const float* __restrict__ vcache, const int* __restrict__ positions,
    const int* __restrict__ btab, float* __restrict__ part) {
  const int b = blockIdx.x, kv = blockIdx.y, ck = blockIdx.z;
  const int tid = threadIdx.x;
  const int hw = tid >> 5, ln = tid & 31;
  const int pos = positions[b];
  const int c0 = ck * CHUNK_;
  float* pout = part + ((size_t)(b * 8 + kv) * NCHUNK + ck) * 4 * 132;

  __shared__ float s_lds[CHUNK_ * 4];
  __shared__ int   slot_lds[CHUNK_];
  __shared__ float red[8 * 512];
  __shared__ float ml[8];

  if (c0 > pos) {  // fully-masked chunk: m=-FLT_MAX, l=0, acc=0
    for (int o = tid; o < 4 * 132; o += 256) pout[o] = 0.f;
    if (tid < 4) pout[tid * 132] = -FLT_MAX;
    return;
  }
  const int nrow = min(CHUNK_, pos + 1 - c0);

  for (int i = tid; i < CHUNK_ * 4; i += 256) s_lds[i] = -FLT_MAX;
  __syncthreads();

  float4 qf[4];
#pragma unroll
  for (int g = 0; g < 4; ++g)
    qf[g] = *reinterpret_cast<const float4*>(
        qr + (size_t)b * 4096 + (size_t)(kv * 4 + g) * 128 + 4 * ln);
  const float scale = 0.08838834764831845f;

  // Phase A: scores
  for (int r = hw; r < nrow; r += 8) {
    int j = c0 + r;
    int slot = btab[b * MAXB_ + (j >> 4)] * BS_ + (j & 15);
    if (ln == 0) slot_lds[r] = slot;
    const float4 kf = *reinterpret_cast<const float4*>(
        kcache + ((size_t)slot * NKV_ + kv) * HD_ + 4 * ln);
#pragma unroll
    for (int g = 0; g < 4; ++g) {
      float s = qf[g].x * kf.x + qf[g].y * kf.y + qf[g].z * kf.z + qf[g].w * kf.w;
      s += __shfl_xor(s, 16); s += __shfl_xor(s, 8); s += __shfl_xor(s, 4);
      s += __shfl_xor(s, 2);  s += __shfl_xor(s, 1);
      if (ln == 0) s_lds[r * 4 + g] = s * scale;
    }
  }
  __syncthreads();

  // softmax partial: wave w owns head-group g=w, 64 lanes cover 256 rows
  {
    int w = tid >> 6, lane = tid & 63;
    float v0 = s_lds[lane * 4 + w];
    float v1 = s_lds[(lane + 64) * 4 + w];
    float v2 = s_lds[(lane + 128) * 4 + w];
    float v3 = s_lds[(lane + 192) * 4 + w];
    float m = fmaxf(fmaxf(v0, v1), fmaxf(v2, v3));
#pragma unroll
    for (int off = 32; off; off >>= 1) m = fmaxf(m, __shfl_xor(m, off));
    float p0 = __expf(v0 - m), p1 = __expf(v1 - m);
    float p2 = __expf(v2 - m), p3 = __expf(v3 - m);
    float l = p0 + p1 + p2 + p3;
#pragma unroll
    for (int off = 32; off; off >>= 1) l += __shfl_xor(l, off);
    s_lds[lane * 4 + w] = p0;
    s_lds[(lane + 64) * 4 + w] = p1;
    s_lds[(lane + 128) * 4 + w] = p2;
    s_lds[(lane + 192) * 4 + w] = p3;
    if (lane == 0) { ml[w] = m; ml[4 + w] = l; }
  }
  __syncthreads();

  // Phase B: P·V
  float acc[4][4];
#pragma unroll
  for (int g = 0; g < 4; ++g)
#pragma unroll
    for (int i = 0; i < 4; ++i) acc[g][i] = 0.f;
  for (int r = hw; r < nrow; r += 8) {
    int slot = slot_lds[r];
    const float4 vf = *reinterpret_cast<const float4*>(
        vcache + ((size_t)slot * NKV_ + kv) * HD_ + 4 * ln);
#pragma unroll
    for (int g = 0; g < 4; ++g) {
      float pg = s_lds[r * 4 + g];
      acc[g][0] = fmaf(pg, vf.x, acc[g][0]);
      acc[g][1] = fmaf(pg, vf.y, acc[g][1]);
      acc[g][2] = fmaf(pg, vf.z, acc[g][2]);
      acc[g][3] = fmaf(pg, vf.w, acc[g][3]);
    }
  }
#pragma unroll
  for (int g = 0; g < 4; ++g) {
    red[hw * 512 + g * 128 + 4 * ln + 0] = acc[g][0];
    red[hw * 512 + g * 128 + 4 * ln + 1] = acc[g][1];
    red[hw * 512 + g * 128 + 4 * ln + 2] = acc[g][2];
    red[hw * 512 + g * 128 + 4 * ln + 3] = acc[g][3];
  }
  __syncthreads();
  for (int o = tid; o < 512; o += 256) {
    float s = 0.f;
#pragma unroll
    for (int h = 0; h < 8; ++h) s += red[h * 512 + o];
    int g = o >> 7, d = o & 127;
    pout[g * 132 + 2 + d] = s;
  }
  if (tid < 4) { pout[tid * 132 + 0] = ml[tid]; pout[tid * 132 + 1] = ml[4 + tid]; }
}

// ---------------- Kernel 4: merge attention chunks ----------------
// grid (32, 8), block 256
__global__ __launch_bounds__(256) void k_attn_reduce(
    const float* __restrict__ part, float* __restrict__ attnO) {
  const int b = blockIdx.x, kv = blockIdx.y;
  const float* pb = part + (size_t)(b * 8 + kv) * NCHUNK * 4 * 132;
  for (int o = threadIdx.x; o < 512; o += 256) {
    int g = o >> 7, d = o & 127;
    float m = -FLT_MAX;
#pragma unroll
    for (int c = 0; c < NCHUNK; ++c) m = fmaxf(m, pb[(c * 4 + g) * 132]);
    float l = 0.f, s = 0.f;
#pragma unroll
    for (int c = 0; c < NCHUNK; ++c) {
      float mc = pb[(c * 4 + g) * 132];
      float wgt = __expf(mc - m);
      l = fmaf(pb[(c * 4 + g) * 132 + 1], wgt, l);
      s = fmaf(pb[(c * 4 + g) * 132 + 2 + d], wgt, s);
    }
    attnO[(size_t)b * 4096 + (size_t)(kv * 4 + g) * 128 + d] = s / l;
  }
}

// ---------------- Kernel 5: output GEMM split-K partials ----------------
// grid (16, KS2), block 256. Same named-accumulator structure as kernel 1.
__global__ __launch_bounds__(256) void k_oproj_partial(
    const float* __restrict__ attnO, const float* __restrict__ wo,
    float* __restrict__ part) {
  const int col = blockIdx.x * 256 + threadIdx.x;
  const int kc  = blockIdx.y;
  const int h0  = kc * HCH2;
#define DECL(i) float a##i = 0.f;
  REP32(DECL)
#undef DECL
  const float* wp = wo + (size_t)h0 * 4096 + col;
  const float* hp = attnO + h0;
#pragma unroll 4
  for (int h = 0; h < HCH2; ++h) {
    float wv = wp[(size_t)h * 4096];
#define FMA(i) a##i = fmaf(hp[i * 4096 + h], wv, a##i);
    REP32(FMA)
#undef FMA
  }
  float* pp = part + (size_t)kc * 32 * 4096 + col;
#define ST(i) pp[(size_t)i * 4096] = a##i;
  REP32(ST)
#undef ST
}

// ---------------- Kernel 6: final reduce ----------------
// 32*4096 = 131072 outputs; grid 512 x 256
__global__ __launch_bounds__(256) void k_final_reduce(
    const float* __restrict__ part, float* __restrict__ out) {
  size_t idx = (size_t)blockIdx.x * 256 + threadIdx.x;
  float s = 0.f;
#pragma unroll
  for (int kc = 0; kc < KS2; ++kc) s += part[(size_t)kc * 131072 + idx];
  out[idx] = s;
}

extern "C" void kernel_launch(void* const* d_in, const int* in_sizes, int n_in,
                              void* d_out, int out_size, void* d_ws, size_t ws_size,
                              hipStream_t stream) {
  const float* hidden = (const float*)d_in[0];
  const float* w_qkv  = (const float*)d_in[1];
  const float* w_o    = (const float*)d_in[2];
  float* k_cache      = (float*)d_in[3];
  float* v_cache      = (float*)d_in[4];
  const int* positions = (const int*)d_in[5];
  const int* btab      = (const int*)d_in[6];
  const int* loc       = (const int*)d_in[7];

  float* ws   = (float*)d_ws;
  float* qkvP = ws + OFF_QKVP;
  float* qR   = ws + OFF_QR;
  float* attP = ws + OFF_ATTP;
  float* attO = ws + OFF_ATTO;
  float* oP   = ws + OFF_OP;
  float* out  = (float*)d_out;

  k_qkv_partial<<<dim3(QKVC_ / 256, KS1), 256, 0, stream>>>(hidden, w_qkv, qkvP);
  k_rope_scatter<<<dim3(B_, 6), 256, 0, stream>>>(qkvP, positions, loc, qR, k_cache, v_cache);
  k_attn_partial<<<dim3(B_, NKV_, NCHUNK), 256, 0, stream>>>(qR, k_cache, v_cache,
                                                             positions, btab, attP);
  k_attn_reduce<<<dim3(B_, NKV_), 256, 0, stream>>>(attP, attO);
  k_oproj_partial<<<dim3(4096 / 256, KS2), 256, 0, stream>>>(attO, w_o, oP);
  k_final_reduce<<<512, 256, 0, stream>>>(oP, out);
}